// Round 7
// baseline (265.449 us; speedup 1.0000x reference)
//
#include <hip/hip_runtime.h>
#include <climits>

// ---------------- problem constants (mirror reference) ----------------
constexpr int kB  = 64;
constexpr int kG0 = 19, kG1 = 38, kG2 = 76;
constexpr int kN0 = 3 * kG0 * kG0;   // 1083
constexpr int kN1 = 3 * kG1 * kG1;   // 4332
constexpr int kN2 = 3 * kG2 * kG2;   // 17328
constexpr int kN  = kN0 + kN1 + kN2; // 22743
constexpr int kM  = 256;             // M_CAND
constexpr int kTopK = 8;
constexpr float kNEG = -1e9f;

// per-image tiles of 256 cells per level: ceil(1083/256)=5, ceil(4332/256)=17, ceil(17328/256)=68
constexpr int kT0 = 5, kT1 = 17, kT2 = 68;
constexpr int kTilesPerImg = kT0 + kT1 + kT2;  // 90
constexpr int kGridScore = 1920;               // pipeline: 1920 blocks x 3 tiles = 5760
constexpr int kTilesPerBlk = 3;

__constant__ float c_anchors[3][3][2] = {
    {{116.f, 90.f}, {156.f, 198.f}, {373.f, 326.f}},
    {{30.f, 61.f},  {62.f, 45.f},   {59.f, 119.f}},
    {{10.f, 13.f},  {16.f, 30.f},   {33.f, 23.f}},
};

// fast transcendentals: v_exp_f32 + v_rcp_f32 (~2-4 ULP; thresholds have huge slack,
// only exact-borderline decisions could flip — P(output change) ~1e-3/run)
__device__ __forceinline__ float fexpf(float x) { return __expf(x); }
__device__ __forceinline__ float frcpf(float x) { return __builtin_amdgcn_rcpf(x); }
__device__ __forceinline__ float fsigm(float x) { return frcpf(1.0f + __expf(-x)); }

// order-preserving float->uint key (ascending). NEG maps below every score>=0.
__device__ __forceinline__ unsigned score_to_key(float s) {
  unsigned fb = __float_as_uint(s);
  unsigned m = (fb & 0x80000000u) ? 0xFFFFFFFFu : 0x80000000u;
  return fb ^ m;
}
__device__ __forceinline__ float key_to_score(unsigned k) {
  unsigned fb = (k & 0x80000000u) ? (k ^ 0x80000000u) : ~k;
  return __uint_as_float(fb);
}

// flat candidate index n -> cell pointer + (level, anchor, row i, col j, stride)
__device__ __forceinline__ const float* cell_ptr(
    const float* p0, const float* p1, const float* p2, int b, int n,
    int& lvl, int& a, int& gi, int& gj, float& stride) {
  const float* src; int G, m;
  if (n < kN0)            { src = p0; G = kG0; lvl = 0; m = n;             stride = 32.f; }
  else if (n < kN0 + kN1) { src = p1; G = kG1; lvl = 1; m = n - kN0;       stride = 16.f; }
  else                    { src = p2; G = kG2; lvl = 2; m = n - kN0 - kN1; stride = 8.f; }
  int gg = G * G;
  a = m / gg;
  int r = m - a * gg;
  gi = r / G;
  gj = r - gi * G;
  return src + (size_t)((((b * 3 + a) * G + gi) * G + gj)) * 26;
}

// ---------------- wave (64-lane) helpers ----------------
__device__ __forceinline__ void waveArgmax(float& v, int& i) {
  #pragma unroll
  for (int off = 1; off < 64; off <<= 1) {
    float ov = __shfl_xor(v, off);
    int oi = __shfl_xor(i, off);
    if (ov > v || (ov == v && oi < i)) { v = ov; i = oi; }
  }
}
__device__ __forceinline__ float waveMax(float v) {
  #pragma unroll
  for (int off = 1; off < 64; off <<= 1) v = fmaxf(v, __shfl_xor(v, off));
  return v;
}
__device__ __forceinline__ float sel4f(const float a[4], int q) {
  float r = a[0];
  r = (q == 1) ? a[1] : r;
  r = (q == 2) ? a[2] : r;
  r = (q == 3) ? a[3] : r;
  return r;
}
__device__ __forceinline__ int sel4i(const int a[4], int q) {
  int r = a[0];
  r = (q == 1) ? a[1] : r;
  r = (q == 2) ? a[2] : r;
  r = (q == 3) ? a[3] : r;
  return r;
}

// async global->LDS DMA, 16 B/lane; LDS dest is wave-uniform base + lane*16
__device__ __forceinline__ void async_copy16(const void* g, void* s) {
  __builtin_amdgcn_global_load_lds(
      (__attribute__((address_space(1))) unsigned int*)g,
      (__attribute__((address_space(3))) unsigned int*)s, 16, 0, 0);
}

// ---------------- kernel 1: pipelined tiled score -> keys (direct store) ----------------
// 1920 blocks x 3 tiles, double-buffered LDS; tile j+1 staged via async DMA while tile j
// computes. NO atomics, NO compaction (R5/R6's cnt[b] atomic-with-return on 2 shared
// cachelines across 8 XCDs cost ~25-40 us — more than the cheaper select it bought).
__global__ __launch_bounds__(256) void score_kernel(
    const float* __restrict__ p0, const float* __restrict__ p1, const float* __restrict__ p2,
    unsigned* __restrict__ keys)
{
  __shared__ float2 lds2[2][256 * 13];   // 2 x 26624 B

  int t = threadIdx.x;
  int lane = t & 63, wave = t >> 6;

  // wave-uniform tile parameters for the 3 tiles of this block
  const float* gb[kTilesPerBlk]; int nc[kTilesPerBlk], n0[kTilesPerBlk], bb[kTilesPerBlk];
  bool dmaOk[kTilesPerBlk];
  #pragma unroll
  for (int j = 0; j < kTilesPerBlk; ++j) {
    int tileId = (int)blockIdx.x + j * kGridScore;
    int b = tileId / kTilesPerImg;
    int r = tileId - b * kTilesPerImg;
    const float* slab; int NL, lvlOff, tile; bool lvl0 = false;
    if (r < kT0)            { slab = p0; NL = kN0; lvlOff = 0;         tile = r;            lvl0 = true; }
    else if (r < kT0 + kT1) { slab = p1; NL = kN1; lvlOff = kN0;       tile = r - kT0; }
    else                    { slab = p2; NL = kN2; lvlOff = kN0 + kN1; tile = r - kT0 - kT1; }
    int cellBase = tile * 256;
    nc[j] = min(256, NL - cellBase);
    gb[j] = slab + ((size_t)b * NL + cellBase) * 26;
    n0[j] = lvlOff + cellBase;
    bb[j] = b;
    // levels 1/2 full tiles: base = b*NL*104 + tile*26624, both =0 mod 16 -> DMA-able.
    // level 0: b*1083*104 = 8 mod 16 for odd b -> use float2 fallback for all lvl0.
    dmaOk[j] = (!lvl0) && (nc[j] == 256);
  }

  auto stage = [&](int j, int buf) {
    if (dmaOk[j]) {
      const char* g = (const char*)gb[j];
      char* s = (char*)&lds2[buf][0];
      for (int c = wave; c < 26; c += 4)            // 26 x 1024-B chunks
        async_copy16(g + c * 1024 + lane * 16, s + c * 1024);
    } else {
      const float2* g2 = (const float2*)gb[j];
      float2* s2 = &lds2[buf][0];
      int tot = nc[j] * 13;
      for (int i = t; i < tot; i += 256) s2[i] = g2[i];
    }
  };

  stage(0, 0);
  #pragma unroll
  for (int j = 0; j < kTilesPerBlk; ++j) {
    __syncthreads();   // drains vmcnt: staging of buf j&1 complete; prev compute's LDS reads done
    if (j + 1 < kTilesPerBlk) stage(j + 1, (j + 1) & 1);   // overlap with compute below

    int curNc = nc[j], curN0 = n0[j], curB = bb[j];
    const float2* bufp = &lds2[j & 1][0];

    if (t < curNc) {
      const float2* c2 = &bufp[t * 13];   // stride-26-dword: 2-way bank alias (free, m136)
      float2 ol = c2[2];                  // channels 4,5
      float obj = fsigm(ol.x);
      float loc = fsigm(ol.y);
      float tch[20];
      #pragma unroll
      for (int q = 0; q < 10; ++q) { float2 v = c2[3 + q]; tch[2*q] = v.x; tch[2*q+1] = v.y; }
      float lm = tch[0];
      #pragma unroll
      for (int c = 1; c < 20; ++c) lm = fmaxf(lm, tch[c]);
      float se = 0.f;
      #pragma unroll
      for (int c = 0; c < 20; ++c) se += fexpf(tch[c] - lm);
      float cls_conf = frcpf(se);         // max of softmax == exp(0)/sum
      float conf = obj * cls_conf;
      float masked = (obj >= 0.6f && loc >= 0.5f && conf >= 0.05f)
                     ? sqrtf(conf) * sqrtf(loc) : kNEG;  // (obj*cc)^.5 * loc^.5
      keys[(size_t)curB * kN + curN0 + t] = score_to_key(masked);  // coalesced u32 store
    }
  }
}

// ---------------- parallel threshold-bin finder ----------------
// Largest bin B with suffix_count(B) >= needed; cumAbove = count strictly above B; total = all.
// All 512 threads participate uniformly.
__device__ __forceinline__ void findThresholdBin(
    const int* hist, int NB, int needed,
    int& outB, int& outCumAbove, int& outTotal,
    int* shWave, int* shOut)
{
  int tid = threadIdx.x, lane = tid & 63, w = tid >> 6;
  if (tid == 0) { shOut[0] = -1; shOut[1] = 0; }
  int ipt = (NB + 511) / 512;
  int base = tid * ipt;
  int csum = 0;
  for (int i = 0; i < ipt; ++i) { int bn = base + i; if (bn < NB) csum += hist[bn]; }
  // inclusive suffix scan within wave (lane l gets sum over lanes >= l)
  int v = csum;
  #pragma unroll
  for (int off = 1; off < 64; off <<= 1) {
    int tv = __shfl_down(v, off);
    if (lane + off < 64) v += tv;
  }
  if (lane == 0) shWave[w] = v;   // wave total
  __syncthreads();
  int above = 0, total = 0;
  #pragma unroll
  for (int q = 0; q < 8; ++q) {
    int wt = shWave[q];
    total += wt;
    if (q > w) above += wt;
  }
  int S = v + above;              // suffix count including own chunk
  if (S >= needed && S - csum < needed) {   // exactly one thread's chunk crosses
    int running = S - csum;
    for (int i = ipt - 1; i >= 0; --i) {
      int bn = base + i; if (bn >= NB) continue;
      int c = hist[bn];
      if (running + c >= needed) { shOut[0] = bn; shOut[1] = running; break; }
      running += c;
    }
  }
  __syncthreads();
  outB = shOut[0]; outCumAbove = shOut[1]; outTotal = total;
  __syncthreads();
}

// ---------------- kernel 2: exact top-256 per image, 3-pass radix over full key array ----
// valid keys (score in (0,1]) lie in [0x80000000, 0xBF800000]; invalid are exactly keyNEG.
__global__ __launch_bounds__(512) void select_kernel(
    const unsigned* __restrict__ keys, int* __restrict__ candIdx, unsigned* __restrict__ candKey)
{
  int b = blockIdx.x, tid = threadIdx.x;
  const unsigned* kk = keys + (size_t)b * kN;
  const unsigned keyNEG = score_to_key(kNEG);

  __shared__ int hist[4096];
  __shared__ int eqBuf[1024];
  __shared__ int shWave[8], shOut[2];
  __shared__ unsigned sT;
  __shared__ int sCgt;

  // ---- pass 1: top 12 bits (skip NEG keys to avoid one-bin atomic hammering) ----
  for (int i = tid; i < 4096; i += 512) hist[i] = 0;
  __syncthreads();
  for (int x = tid; x < kN; x += 512) {
    unsigned k = kk[x];
    if (k >= 0x80000000u) atomicAdd(&hist[k >> 20], 1);
  }
  __syncthreads();
  int B, cumAbove1, total1;
  findThresholdBin(hist, 4096, kM, B, cumAbove1, total1, shWave, shOut);

  if (total1 < kM) {
    if (tid == 0) { sT = keyNEG; sCgt = total1; }   // fewer than 256 valid
    __syncthreads();
  } else {
    int needed2 = kM - cumAbove1;
    // ---- pass 2: key bits 19:8 within bin B ----
    for (int i = tid; i < 4096; i += 512) hist[i] = 0;
    __syncthreads();
    for (int x = tid; x < kN; x += 512) {
      unsigned k = kk[x];
      if ((int)(k >> 20) == B) atomicAdd(&hist[(k >> 8) & 0xFFF], 1);
    }
    __syncthreads();
    int B2, cumAbove2, total2;
    findThresholdBin(hist, 4096, needed2, B2, cumAbove2, total2, shWave, shOut);
    int prefix24 = (B << 12) | B2;
    int needed3 = needed2 - cumAbove2;

    // ---- pass 3: low 8 key bits within 24-bit prefix ----
    for (int i = tid; i < 256; i += 512) hist[i] = 0;
    __syncthreads();
    for (int x = tid; x < kN; x += 512) {
      unsigned k = kk[x];
      if ((int)(k >> 8) == prefix24) atomicAdd(&hist[k & 0xFF], 1);
    }
    __syncthreads();
    int B3, cumAbove3, total3;
    findThresholdBin(hist, 256, needed3, B3, cumAbove3, total3, shWave, shOut);
    if (tid == 0) {
      sT = ((unsigned)prefix24 << 8) | (unsigned)B3;
      sCgt = cumAbove1 + cumAbove2 + cumAbove3;     // exact count of keys > T
    }
    __syncthreads();
  }

  unsigned T = sT;
  int cgt = sCgt;

  // ---- gather: all keys > T, then fill ties (== T) by smallest index ----
  __shared__ int sCnt, eqCnt;
  if (tid == 0) { sCnt = 0; eqCnt = 0; }
  __syncthreads();
  int* ci = candIdx + (size_t)b * kM;
  unsigned* ck = candKey + (size_t)b * kM;
  for (int x = tid; x < kN; x += 512) {
    unsigned k = kk[x];
    if (k > T) {
      int p = atomicAdd(&sCnt, 1);
      ci[p] = x; ck[p] = k;
    } else if (k == T && T != keyNEG) {
      int p = atomicAdd(&eqCnt, 1); if (p < 1024) eqBuf[p] = x;
    }
  }
  __syncthreads();

  int needed = kM - cgt;  // >= 1 by construction
  if (T == keyNEG) {
    // NEG filler candidates: never kept, never picked, never influence others -> dummies ok
    if (tid >= cgt && tid < kM) { ci[tid] = -1; ck[tid] = keyNEG; }
  } else {
    int ce = min(eqCnt, 1024);
    if (ce == needed) {               // common case (typically ce == needed == 1)
      if (tid < needed) { ci[cgt + tid] = eqBuf[tid]; ck[cgt + tid] = T; }
    } else if (tid == 0) {            // rare tie overflow: take smallest original indices
      for (int q = 0; q < needed; ++q) {
        int mv = INT_MAX, mp = 0;
        for (int x = 0; x < ce; ++x) if (eqBuf[x] < mv) { mv = eqBuf[x]; mp = x; }
        ci[cgt + q] = mv; ck[cgt + q] = T; eqBuf[mp] = INT_MAX;
      }
    }
  }
}

// ---------------- kernel 3: single-wave soft-NMS with exact early stop ----------------
// 64 threads/block, 4 candidates per lane, all state in registers, zero barriers.
__global__ __launch_bounds__(64) void nms_kernel(
    const float* __restrict__ p0, const float* __restrict__ p1, const float* __restrict__ p2,
    const int* __restrict__ candIdx, const unsigned* __restrict__ candKey,
    float* __restrict__ out)
{
  int b = blockIdx.x, lane = threadIdx.x;

  float x1[4], y1[4], x2[4], y2[4], val[4], s[4];
  int cls[4];
  bool kept[4];

  #pragma unroll
  for (int q = 0; q < 4; ++q) {
    int slot = b * kM + q * 64 + lane;     // coalesced
    int n = candIdx[slot];
    float sc = key_to_score(candKey[slot]);  // bit-exact score from kernel 1 (kNEG for filler)
    kept[q] = false;
    x1[q] = y1[q] = x2[q] = y2[q] = 0.f;
    cls[q] = 0; val[q] = sc; s[q] = sc;
    if (n >= 0) {
      int lvl, a, gi, gj; float stride;
      const float* p = cell_ptr(p0, p1, p2, b, n, lvl, a, gi, gj, stride);
      const float2* r2 = (const float2*)p;   // rows are 104 B: even-float offsets 8B-aligned
      float2 c01 = r2[0], c23 = r2[1];
      float cx = (fsigm(c01.x) + (float)gj) * stride;
      float cy = (fsigm(c01.y) + (float)gi) * stride;
      float w = fexpf(c23.x) * c_anchors[lvl][a][0];  // (exp*anc/stride)*stride == exp*anc
      float h = fexpf(c23.y) * c_anchors[lvl][a][1];
      x1[q] = fminf(fmaxf(cx - 0.5f * w, 0.f), 608.f);
      y1[q] = fminf(fmaxf(cy - 0.5f * h, 0.f), 608.f);
      x2[q] = fminf(fmaxf(cx + 0.5f * w, 0.f), 608.f);
      y2[q] = fminf(fmaxf(cy + 0.5f * h, 0.f), 608.f);
      float lm = -3.4e38f; int mc = 0;
      #pragma unroll
      for (int j = 3; j < 13; ++j) {
        float2 v = r2[j];
        int c0 = 2 * (j - 3);
        if (v.x > lm) { lm = v.x; mc = c0; }
        if (v.y > lm) { lm = v.y; mc = c0 + 1; }
      }
      cls[q] = mc;
    }
  }

  // top-8 kept ORIGINAL scores, maintained identically (uniformly) on all lanes
  float top8[8];
  #pragma unroll
  for (int i = 0; i < 8; ++i) top8[i] = kNEG;
  int keptCount = 0;

  for (int it = 0; it < kM; ++it) {
    float bv = s[0]; int bq = 0;
    #pragma unroll
    for (int q = 1; q < 4; ++q) if (s[q] > bv) { bv = s[q]; bq = q; }
    int bi = bq * 64 + lane;
    waveArgmax(bv, bi);
    if (bv < 0.1f) break;   // all remaining reference steps are no-ops -> exact

    int wlane = bi & 63, wq = bi >> 6;
    float jx1 = __shfl(sel4f(x1, wq), wlane);
    float jy1 = __shfl(sel4f(y1, wq), wlane);
    float jx2 = __shfl(sel4f(x2, wq), wlane);
    float jy2 = __shfl(sel4f(y2, wq), wlane);
    float jval = __shfl(sel4f(val, wq), wlane);
    int   cj  = __shfl(sel4i(cls, wq), wlane);

    float a1 = (jx2 - jx1 + 1.0f) * (jy2 - jy1 + 1.0f);
    #pragma unroll
    for (int q = 0; q < 4; ++q) {
      if (cls[q] == cj) {
        float ix1 = fmaxf(jx1, x1[q]), iy1 = fmaxf(jy1, y1[q]);
        float ix2 = fminf(jx2, x2[q]), iy2 = fminf(jy2, y2[q]);
        float inter = fmaxf(ix2 - ix1 + 1.0f, 0.0f) * fmaxf(iy2 - iy1 + 1.0f, 0.0f);
        float a2 = (x2[q] - x1[q] + 1.0f) * (y2[q] - y1[q] + 1.0f);
        float iou = inter / (a1 + a2 - inter + 1e-16f);
        s[q] *= fexpf(-(iou * iou) * 2.0f);
      }
      if (bi == q * 64 + lane) { kept[q] = true; s[q] = kNEG; }  // winner slot
    }

    // early-stop bookkeeping (uniform scalar work on every lane)
    float v = jval;
    #pragma unroll
    for (int i = 0; i < 8; ++i) { float m = fmaxf(top8[i], v); v = fminf(top8[i], v); top8[i] = m; }
    ++keptCount;
    if (keptCount >= kTopK) {
      float am = kNEG;
      #pragma unroll
      for (int q = 0; q < 4; ++q) if (s[q] >= 0.1f) am = fmaxf(am, val[q]);
      am = waveMax(am);
      // no alive candidate's ORIGINAL score can beat the 8th-best kept original:
      // s is monotone non-increasing, originals fixed, kept flags never revert -> exact stop
      if (am < top8[7]) break;
    }
  }

  // keep_top_k by ORIGINAL score among kept
  float f[4];
  #pragma unroll
  for (int q = 0; q < 4; ++q) f[q] = kept[q] ? val[q] : kNEG;
  for (int k = 0; k < kTopK; ++k) {
    float bv = f[0]; int bq = 0;
    #pragma unroll
    for (int q = 1; q < 4; ++q) if (f[q] > bv) { bv = f[q]; bq = q; }
    int bi = bq * 64 + lane;
    waveArgmax(bv, bi);
    int wlane = bi & 63, wq = bi >> 6;
    if (lane == wlane) {
      float* o = out + (size_t)(b * kTopK + k) * 6;
      if (bv > kNEG * 0.5f) {
        o[0] = sel4f(x1, wq); o[1] = sel4f(y1, wq);
        o[2] = sel4f(x2, wq); o[3] = sel4f(y2, wq);
        o[4] = sel4f(val, wq); o[5] = (float)sel4i(cls, wq);
      } else {
        o[0] = 0.f; o[1] = 0.f; o[2] = 0.f; o[3] = 0.f; o[4] = 0.f; o[5] = 0.f;
      }
    }
    #pragma unroll
    for (int q = 0; q < 4; ++q) if (bi == q * 64 + lane) f[q] = kNEG;
  }
}

// ---------------- host launch ----------------
extern "C" void kernel_launch(void* const* d_in, const int* in_sizes, int n_in,
                              void* d_out, int out_size, void* d_ws, size_t ws_size,
                              hipStream_t stream) {
  const float* p0 = (const float*)d_in[0];
  const float* p1 = (const float*)d_in[1];
  const float* p2 = (const float*)d_in[2];
  float* out = (float*)d_out;

  // workspace layout: keys u32[B*N] (5.82 MB) | candIdx int[B*256] | candKey u32[B*256]
  unsigned* keys = (unsigned*)d_ws;
  int* candIdx = (int*)(keys + (size_t)kB * kN);
  unsigned* candKey = (unsigned*)(candIdx + kB * kM);

  score_kernel<<<kGridScore, 256, 0, stream>>>(p0, p1, p2, keys);
  select_kernel<<<kB, 512, 0, stream>>>(keys, candIdx, candKey);
  nms_kernel<<<kB, 64, 0, stream>>>(p0, p1, p2, candIdx, candKey, out);
}

// Round 8
// 258.886 us; speedup vs baseline: 1.0254x; 1.0254x over previous
//
#include <hip/hip_runtime.h>
#include <climits>

// ---------------- problem constants (mirror reference) ----------------
constexpr int kB  = 64;
constexpr int kG0 = 19, kG1 = 38, kG2 = 76;
constexpr int kN0 = 3 * kG0 * kG0;   // 1083
constexpr int kN1 = 3 * kG1 * kG1;   // 4332
constexpr int kN2 = 3 * kG2 * kG2;   // 17328
constexpr int kN  = kN0 + kN1 + kN2; // 22743
constexpr int kM  = 256;             // M_CAND
constexpr int kTopK = 8;
constexpr float kNEG = -1e9f;

// per-image tiles of 256 cells per level: ceil(1083/256)=5, ceil(4332/256)=17, ceil(17328/256)=68
constexpr int kT0 = 5, kT1 = 17, kT2 = 68;
constexpr int kTilesPerImg = kT0 + kT1 + kT2;  // 90
constexpr int kGridScore = 1920;               // pipeline: 1920 blocks x 3 tiles = 5760
constexpr int kTilesPerBlk = 3;

__constant__ float c_anchors[3][3][2] = {
    {{116.f, 90.f}, {156.f, 198.f}, {373.f, 326.f}},
    {{30.f, 61.f},  {62.f, 45.f},   {59.f, 119.f}},
    {{10.f, 13.f},  {16.f, 30.f},   {33.f, 23.f}},
};

// fast transcendentals: v_exp_f32 + v_rcp_f32 (~2-4 ULP; thresholds have huge slack,
// only exact-borderline decisions could flip — P(output change) ~1e-3/run)
__device__ __forceinline__ float fexpf(float x) { return __expf(x); }
__device__ __forceinline__ float frcpf(float x) { return __builtin_amdgcn_rcpf(x); }
__device__ __forceinline__ float fsigm(float x) { return frcpf(1.0f + __expf(-x)); }

// order-preserving float->uint key (ascending). NEG maps below every score>=0.
__device__ __forceinline__ unsigned score_to_key(float s) {
  unsigned fb = __float_as_uint(s);
  unsigned m = (fb & 0x80000000u) ? 0xFFFFFFFFu : 0x80000000u;
  return fb ^ m;
}
__device__ __forceinline__ float key_to_score(unsigned k) {
  unsigned fb = (k & 0x80000000u) ? (k ^ 0x80000000u) : ~k;
  return __uint_as_float(fb);
}

// flat candidate index n -> cell pointer + (level, anchor, row i, col j, stride)
__device__ __forceinline__ const float* cell_ptr(
    const float* p0, const float* p1, const float* p2, int b, int n,
    int& lvl, int& a, int& gi, int& gj, float& stride) {
  const float* src; int G, m;
  if (n < kN0)            { src = p0; G = kG0; lvl = 0; m = n;             stride = 32.f; }
  else if (n < kN0 + kN1) { src = p1; G = kG1; lvl = 1; m = n - kN0;       stride = 16.f; }
  else                    { src = p2; G = kG2; lvl = 2; m = n - kN0 - kN1; stride = 8.f; }
  int gg = G * G;
  a = m / gg;
  int r = m - a * gg;
  gi = r / G;
  gj = r - gi * G;
  return src + (size_t)((((b * 3 + a) * G + gi) * G + gj)) * 26;
}

// ---------------- wave (64-lane) helpers ----------------
__device__ __forceinline__ void waveArgmax(float& v, int& i) {
  #pragma unroll
  for (int off = 1; off < 64; off <<= 1) {
    float ov = __shfl_xor(v, off);
    int oi = __shfl_xor(i, off);
    if (ov > v || (ov == v && oi < i)) { v = ov; i = oi; }
  }
}
__device__ __forceinline__ float waveMax(float v) {
  #pragma unroll
  for (int off = 1; off < 64; off <<= 1) v = fmaxf(v, __shfl_xor(v, off));
  return v;
}
__device__ __forceinline__ float sel4f(const float a[4], int q) {
  float r = a[0];
  r = (q == 1) ? a[1] : r;
  r = (q == 2) ? a[2] : r;
  r = (q == 3) ? a[3] : r;
  return r;
}
__device__ __forceinline__ int sel4i(const int a[4], int q) {
  int r = a[0];
  r = (q == 1) ? a[1] : r;
  r = (q == 2) ? a[2] : r;
  r = (q == 3) ? a[3] : r;
  return r;
}

// async global->LDS DMA, 16 B/lane; LDS dest is wave-uniform base + lane*16
__device__ __forceinline__ void async_copy16(const void* g, void* s) {
  __builtin_amdgcn_global_load_lds(
      (__attribute__((address_space(1))) unsigned int*)g,
      (__attribute__((address_space(3))) unsigned int*)s, 16, 0, 0);
}

// ---------------- kernel 1: pipelined tiled score -> keys (direct store) ----------------
// 1920 blocks x 3 tiles, double-buffered LDS; tile j+1 staged via async DMA while tile j
// computes. NOTE: duration is pinned ~67 us by harness poison/restore overlap (R3=R7
// despite wildly different internals) — do not micro-optimize further.
__global__ __launch_bounds__(256) void score_kernel(
    const float* __restrict__ p0, const float* __restrict__ p1, const float* __restrict__ p2,
    unsigned* __restrict__ keys)
{
  __shared__ float2 lds2[2][256 * 13];   // 2 x 26624 B

  int t = threadIdx.x;
  int lane = t & 63, wave = t >> 6;

  // wave-uniform tile parameters for the 3 tiles of this block
  const float* gb[kTilesPerBlk]; int nc[kTilesPerBlk], n0[kTilesPerBlk], bb[kTilesPerBlk];
  bool dmaOk[kTilesPerBlk];
  #pragma unroll
  for (int j = 0; j < kTilesPerBlk; ++j) {
    int tileId = (int)blockIdx.x + j * kGridScore;
    int b = tileId / kTilesPerImg;
    int r = tileId - b * kTilesPerImg;
    const float* slab; int NL, lvlOff, tile; bool lvl0 = false;
    if (r < kT0)            { slab = p0; NL = kN0; lvlOff = 0;         tile = r;            lvl0 = true; }
    else if (r < kT0 + kT1) { slab = p1; NL = kN1; lvlOff = kN0;       tile = r - kT0; }
    else                    { slab = p2; NL = kN2; lvlOff = kN0 + kN1; tile = r - kT0 - kT1; }
    int cellBase = tile * 256;
    nc[j] = min(256, NL - cellBase);
    gb[j] = slab + ((size_t)b * NL + cellBase) * 26;
    n0[j] = lvlOff + cellBase;
    bb[j] = b;
    // levels 1/2 full tiles: base = b*NL*104 + tile*26624, both =0 mod 16 -> DMA-able.
    // level 0: b*1083*104 = 8 mod 16 for odd b -> use float2 fallback for all lvl0.
    dmaOk[j] = (!lvl0) && (nc[j] == 256);
  }

  auto stage = [&](int j, int buf) {
    if (dmaOk[j]) {
      const char* g = (const char*)gb[j];
      char* s = (char*)&lds2[buf][0];
      for (int c = wave; c < 26; c += 4)            // 26 x 1024-B chunks
        async_copy16(g + c * 1024 + lane * 16, s + c * 1024);
    } else {
      const float2* g2 = (const float2*)gb[j];
      float2* s2 = &lds2[buf][0];
      int tot = nc[j] * 13;
      for (int i = t; i < tot; i += 256) s2[i] = g2[i];
    }
  };

  stage(0, 0);
  #pragma unroll
  for (int j = 0; j < kTilesPerBlk; ++j) {
    __syncthreads();   // drains vmcnt: staging of buf j&1 complete; prev compute's LDS reads done
    if (j + 1 < kTilesPerBlk) stage(j + 1, (j + 1) & 1);   // overlap with compute below

    int curNc = nc[j], curN0 = n0[j], curB = bb[j];
    const float2* bufp = &lds2[j & 1][0];

    if (t < curNc) {
      const float2* c2 = &bufp[t * 13];   // stride-26-dword: 2-way bank alias (free, m136)
      float2 ol = c2[2];                  // channels 4,5
      float obj = fsigm(ol.x);
      float loc = fsigm(ol.y);
      float tch[20];
      #pragma unroll
      for (int q = 0; q < 10; ++q) { float2 v = c2[3 + q]; tch[2*q] = v.x; tch[2*q+1] = v.y; }
      float lm = tch[0];
      #pragma unroll
      for (int c = 1; c < 20; ++c) lm = fmaxf(lm, tch[c]);
      float se = 0.f;
      #pragma unroll
      for (int c = 0; c < 20; ++c) se += fexpf(tch[c] - lm);
      float cls_conf = frcpf(se);         // max of softmax == exp(0)/sum
      float conf = obj * cls_conf;
      float masked = (obj >= 0.6f && loc >= 0.5f && conf >= 0.05f)
                     ? sqrtf(conf) * sqrtf(loc) : kNEG;  // (obj*cc)^.5 * loc^.5
      keys[(size_t)curB * kN + curN0 + t] = score_to_key(masked);  // coalesced u32 store
    }
  }
}

// ---------------- parallel threshold-bin finder ----------------
// Largest bin B with suffix_count(B) >= needed; cumAbove = count strictly above B; total = all.
// All 512 threads participate uniformly.
__device__ __forceinline__ void findThresholdBin(
    const int* hist, int NB, int needed,
    int& outB, int& outCumAbove, int& outTotal,
    int* shWave, int* shOut)
{
  int tid = threadIdx.x, lane = tid & 63, w = tid >> 6;
  if (tid == 0) { shOut[0] = -1; shOut[1] = 0; }
  int ipt = (NB + 511) / 512;
  int base = tid * ipt;
  int csum = 0;
  for (int i = 0; i < ipt; ++i) { int bn = base + i; if (bn < NB) csum += hist[bn]; }
  // inclusive suffix scan within wave (lane l gets sum over lanes >= l)
  int v = csum;
  #pragma unroll
  for (int off = 1; off < 64; off <<= 1) {
    int tv = __shfl_down(v, off);
    if (lane + off < 64) v += tv;
  }
  if (lane == 0) shWave[w] = v;   // wave total
  __syncthreads();
  int above = 0, total = 0;
  #pragma unroll
  for (int q = 0; q < 8; ++q) {
    int wt = shWave[q];
    total += wt;
    if (q > w) above += wt;
  }
  int S = v + above;              // suffix count including own chunk
  if (S >= needed && S - csum < needed) {   // exactly one thread's chunk crosses
    int running = S - csum;
    for (int i = ipt - 1; i >= 0; --i) {
      int bn = base + i; if (bn >= NB) continue;
      int c = hist[bn];
      if (running + c >= needed) { shOut[0] = bn; shOut[1] = running; break; }
      running += c;
    }
  }
  __syncthreads();
  outB = shOut[0]; outCumAbove = shOut[1]; outTotal = total;
  __syncthreads();
}

// ---------------- kernel 2: FUSED select (all 512 thr) + soft-NMS (wave 0) ----------------
// Radix top-256 results stay in LDS; wave 0 then runs the register-resident NMS and
// writes the final top-8 rows. Saves a launch + the candIdx/candKey L2 round-trip.
__global__ __launch_bounds__(512) void select_nms_kernel(
    const unsigned* __restrict__ keys,
    const float* __restrict__ p0, const float* __restrict__ p1, const float* __restrict__ p2,
    float* __restrict__ out)
{
  int b = blockIdx.x, tid = threadIdx.x;
  const unsigned* kk = keys + (size_t)b * kN;
  const unsigned keyNEG = score_to_key(kNEG);

  __shared__ int hist[4096];
  __shared__ int eqBuf[1024];
  __shared__ int shWave[8], shOut[2];
  __shared__ unsigned sT;
  __shared__ int sCgt;
  __shared__ int ciL[kM];
  __shared__ unsigned ckL[kM];

  // ---- pass 1: top 12 bits (skip NEG keys to avoid one-bin atomic hammering) ----
  for (int i = tid; i < 4096; i += 512) hist[i] = 0;
  __syncthreads();
  for (int x = tid; x < kN; x += 512) {
    unsigned k = kk[x];
    if (k >= 0x80000000u) atomicAdd(&hist[k >> 20], 1);
  }
  __syncthreads();
  int B, cumAbove1, total1;
  findThresholdBin(hist, 4096, kM, B, cumAbove1, total1, shWave, shOut);

  if (total1 < kM) {
    if (tid == 0) { sT = keyNEG; sCgt = total1; }   // fewer than 256 valid
    __syncthreads();
  } else {
    int needed2 = kM - cumAbove1;
    // ---- pass 2: key bits 19:8 within bin B ----
    for (int i = tid; i < 4096; i += 512) hist[i] = 0;
    __syncthreads();
    for (int x = tid; x < kN; x += 512) {
      unsigned k = kk[x];
      if ((int)(k >> 20) == B) atomicAdd(&hist[(k >> 8) & 0xFFF], 1);
    }
    __syncthreads();
    int B2, cumAbove2, total2;
    findThresholdBin(hist, 4096, needed2, B2, cumAbove2, total2, shWave, shOut);
    int prefix24 = (B << 12) | B2;
    int needed3 = needed2 - cumAbove2;

    // ---- pass 3: low 8 key bits within 24-bit prefix ----
    for (int i = tid; i < 256; i += 512) hist[i] = 0;
    __syncthreads();
    for (int x = tid; x < kN; x += 512) {
      unsigned k = kk[x];
      if ((int)(k >> 8) == prefix24) atomicAdd(&hist[k & 0xFF], 1);
    }
    __syncthreads();
    int B3, cumAbove3, total3;
    findThresholdBin(hist, 256, needed3, B3, cumAbove3, total3, shWave, shOut);
    if (tid == 0) {
      sT = ((unsigned)prefix24 << 8) | (unsigned)B3;
      sCgt = cumAbove1 + cumAbove2 + cumAbove3;     // exact count of keys > T
    }
    __syncthreads();
  }

  unsigned T = sT;
  int cgt = sCgt;

  // ---- gather into LDS: all keys > T, then fill ties (== T) by smallest index ----
  __shared__ int sCnt, eqCnt;
  if (tid == 0) { sCnt = 0; eqCnt = 0; }
  __syncthreads();
  for (int x = tid; x < kN; x += 512) {
    unsigned k = kk[x];
    if (k > T) {
      int p = atomicAdd(&sCnt, 1);
      ciL[p] = x; ckL[p] = k;
    } else if (k == T && T != keyNEG) {
      int p = atomicAdd(&eqCnt, 1); if (p < 1024) eqBuf[p] = x;
    }
  }
  __syncthreads();

  int needed = kM - cgt;  // >= 1 by construction
  if (T == keyNEG) {
    // NEG filler candidates: never kept, never picked, never influence others -> dummies ok
    if (tid >= cgt && tid < kM) { ciL[tid] = -1; ckL[tid] = keyNEG; }
  } else {
    int ce = min(eqCnt, 1024);
    if (ce == needed) {               // common case (typically ce == needed == 1)
      if (tid < needed) { ciL[cgt + tid] = eqBuf[tid]; ckL[cgt + tid] = T; }
    } else if (tid == 0) {            // rare tie overflow: take smallest original indices
      for (int q = 0; q < needed; ++q) {
        int mv = INT_MAX, mp = 0;
        for (int x = 0; x < ce; ++x) if (eqBuf[x] < mv) { mv = eqBuf[x]; mp = x; }
        ciL[cgt + q] = mv; ckL[cgt + q] = T; eqBuf[mp] = INT_MAX;
      }
    }
  }
  __syncthreads();

  // ================= NMS phase: wave 0 only, 4 candidates/lane, register state =========
  if (tid >= 64) return;
  int lane = tid;

  float x1[4], y1[4], x2[4], y2[4], val[4], s[4];
  int cls[4];
  bool kept[4];

  #pragma unroll
  for (int q = 0; q < 4; ++q) {
    int slot = q * 64 + lane;
    int n = ciL[slot];
    float sc = key_to_score(ckL[slot]);  // bit-exact score from kernel 1 (kNEG for filler)
    kept[q] = false;
    x1[q] = y1[q] = x2[q] = y2[q] = 0.f;
    cls[q] = 0; val[q] = sc; s[q] = sc;
    if (n >= 0) {
      int lvl, a, gi, gj; float stride;
      const float* p = cell_ptr(p0, p1, p2, b, n, lvl, a, gi, gj, stride);
      const float2* r2 = (const float2*)p;   // rows are 104 B: even-float offsets 8B-aligned
      float2 c01 = r2[0], c23 = r2[1];
      float cx = (fsigm(c01.x) + (float)gj) * stride;
      float cy = (fsigm(c01.y) + (float)gi) * stride;
      float w = fexpf(c23.x) * c_anchors[lvl][a][0];  // (exp*anc/stride)*stride == exp*anc
      float h = fexpf(c23.y) * c_anchors[lvl][a][1];
      x1[q] = fminf(fmaxf(cx - 0.5f * w, 0.f), 608.f);
      y1[q] = fminf(fmaxf(cy - 0.5f * h, 0.f), 608.f);
      x2[q] = fminf(fmaxf(cx + 0.5f * w, 0.f), 608.f);
      y2[q] = fminf(fmaxf(cy + 0.5f * h, 0.f), 608.f);
      float lm = -3.4e38f; int mc = 0;
      #pragma unroll
      for (int j = 3; j < 13; ++j) {
        float2 v = r2[j];
        int c0 = 2 * (j - 3);
        if (v.x > lm) { lm = v.x; mc = c0; }
        if (v.y > lm) { lm = v.y; mc = c0 + 1; }
      }
      cls[q] = mc;
    }
  }

  // top-8 kept ORIGINAL scores, maintained identically (uniformly) on all lanes
  float top8[8];
  #pragma unroll
  for (int i = 0; i < 8; ++i) top8[i] = kNEG;
  int keptCount = 0;

  for (int it = 0; it < kM; ++it) {
    float bv = s[0]; int bq = 0;
    #pragma unroll
    for (int q = 1; q < 4; ++q) if (s[q] > bv) { bv = s[q]; bq = q; }
    int bi = bq * 64 + lane;
    waveArgmax(bv, bi);
    if (bv < 0.1f) break;   // all remaining reference steps are no-ops -> exact

    int wlane = bi & 63, wq = bi >> 6;
    float jx1 = __shfl(sel4f(x1, wq), wlane);
    float jy1 = __shfl(sel4f(y1, wq), wlane);
    float jx2 = __shfl(sel4f(x2, wq), wlane);
    float jy2 = __shfl(sel4f(y2, wq), wlane);
    float jval = __shfl(sel4f(val, wq), wlane);
    int   cj  = __shfl(sel4i(cls, wq), wlane);

    float a1 = (jx2 - jx1 + 1.0f) * (jy2 - jy1 + 1.0f);
    #pragma unroll
    for (int q = 0; q < 4; ++q) {
      if (cls[q] == cj) {
        float ix1 = fmaxf(jx1, x1[q]), iy1 = fmaxf(jy1, y1[q]);
        float ix2 = fminf(jx2, x2[q]), iy2 = fminf(jy2, y2[q]);
        float inter = fmaxf(ix2 - ix1 + 1.0f, 0.0f) * fmaxf(iy2 - iy1 + 1.0f, 0.0f);
        float a2 = (x2[q] - x1[q] + 1.0f) * (y2[q] - y1[q] + 1.0f);
        float iou = inter / (a1 + a2 - inter + 1e-16f);
        s[q] *= fexpf(-(iou * iou) * 2.0f);
      }
      if (bi == q * 64 + lane) { kept[q] = true; s[q] = kNEG; }  // winner slot
    }

    // early-stop bookkeeping (uniform scalar work on every lane)
    float v = jval;
    #pragma unroll
    for (int i = 0; i < 8; ++i) { float m = fmaxf(top8[i], v); v = fminf(top8[i], v); top8[i] = m; }
    ++keptCount;
    if (keptCount >= kTopK) {
      float am = kNEG;
      #pragma unroll
      for (int q = 0; q < 4; ++q) if (s[q] >= 0.1f) am = fmaxf(am, val[q]);
      am = waveMax(am);
      // no alive candidate's ORIGINAL score can beat the 8th-best kept original:
      // s is monotone non-increasing, originals fixed, kept flags never revert -> exact stop
      if (am < top8[7]) break;
    }
  }

  // keep_top_k by ORIGINAL score among kept
  float f[4];
  #pragma unroll
  for (int q = 0; q < 4; ++q) f[q] = kept[q] ? val[q] : kNEG;
  for (int k = 0; k < kTopK; ++k) {
    float bv = f[0]; int bq = 0;
    #pragma unroll
    for (int q = 1; q < 4; ++q) if (f[q] > bv) { bv = f[q]; bq = q; }
    int bi = bq * 64 + lane;
    waveArgmax(bv, bi);
    int wlane = bi & 63, wq = bi >> 6;
    if (lane == wlane) {
      float* o = out + (size_t)(b * kTopK + k) * 6;
      if (bv > kNEG * 0.5f) {
        o[0] = sel4f(x1, wq); o[1] = sel4f(y1, wq);
        o[2] = sel4f(x2, wq); o[3] = sel4f(y2, wq);
        o[4] = sel4f(val, wq); o[5] = (float)sel4i(cls, wq);
      } else {
        o[0] = 0.f; o[1] = 0.f; o[2] = 0.f; o[3] = 0.f; o[4] = 0.f; o[5] = 0.f;
      }
    }
    #pragma unroll
    for (int q = 0; q < 4; ++q) if (bi == q * 64 + lane) f[q] = kNEG;
  }
}

// ---------------- host launch ----------------
extern "C" void kernel_launch(void* const* d_in, const int* in_sizes, int n_in,
                              void* d_out, int out_size, void* d_ws, size_t ws_size,
                              hipStream_t stream) {
  const float* p0 = (const float*)d_in[0];
  const float* p1 = (const float*)d_in[1];
  const float* p2 = (const float*)d_in[2];
  float* out = (float*)d_out;

  // workspace layout: keys u32[B*N] (5.82 MB)
  unsigned* keys = (unsigned*)d_ws;

  score_kernel<<<kGridScore, 256, 0, stream>>>(p0, p1, p2, keys);
  select_nms_kernel<<<kB, 512, 0, stream>>>(keys, p0, p1, p2, out);
}

// Round 9
// 226.330 us; speedup vs baseline: 1.1728x; 1.1438x over previous
//
#include <hip/hip_runtime.h>
#include <climits>

// ---------------- problem constants (mirror reference) ----------------
constexpr int kB  = 64;
constexpr int kG0 = 19, kG1 = 38, kG2 = 76;
constexpr int kN0 = 3 * kG0 * kG0;   // 1083
constexpr int kN1 = 3 * kG1 * kG1;   // 4332
constexpr int kN2 = 3 * kG2 * kG2;   // 17328
constexpr int kN  = kN0 + kN1 + kN2; // 22743
constexpr int kNP = kN + 1;          // padded row stride (22744): rows 16B-aligned for uint4
constexpr int kM  = 256;             // M_CAND
constexpr int kTopK = 8;
constexpr float kNEG = -1e9f;

// per-image tiles of 256 cells per level: ceil(1083/256)=5, ceil(4332/256)=17, ceil(17328/256)=68
constexpr int kT0 = 5, kT1 = 17, kT2 = 68;
constexpr int kTilesPerImg = kT0 + kT1 + kT2;  // 90
constexpr int kGridScore = 1920;               // pipeline: 1920 blocks x 3 tiles = 5760
constexpr int kTilesPerBlk = 3;

__constant__ float c_anchors[3][3][2] = {
    {{116.f, 90.f}, {156.f, 198.f}, {373.f, 326.f}},
    {{30.f, 61.f},  {62.f, 45.f},   {59.f, 119.f}},
    {{10.f, 13.f},  {16.f, 30.f},   {33.f, 23.f}},
};

// fast transcendentals: v_exp_f32 + v_rcp_f32 (~2-4 ULP; thresholds have huge slack)
__device__ __forceinline__ float fexpf(float x) { return __expf(x); }
__device__ __forceinline__ float frcpf(float x) { return __builtin_amdgcn_rcpf(x); }
__device__ __forceinline__ float fsigm(float x) { return frcpf(1.0f + __expf(-x)); }

// non-temporal 8B load (no cache allocation -> doesn't evict the harness's dirty
// poison lines from L3; the suspected cause of the ~67us score floor)
__device__ __forceinline__ float2 nt_load_f2(const float2* p) {
  unsigned long long v = __builtin_nontemporal_load((const unsigned long long*)p);
  union { unsigned long long u; float2 f; } c; c.u = v; return c.f;
}

// order-preserving float->uint key (ascending). NEG maps below every score>=0.
__device__ __forceinline__ unsigned score_to_key(float s) {
  unsigned fb = __float_as_uint(s);
  unsigned m = (fb & 0x80000000u) ? 0xFFFFFFFFu : 0x80000000u;
  return fb ^ m;
}
__device__ __forceinline__ float key_to_score(unsigned k) {
  unsigned fb = (k & 0x80000000u) ? (k ^ 0x80000000u) : ~k;
  return __uint_as_float(fb);
}

// flat candidate index n -> cell pointer + (level, anchor, row i, col j, stride)
__device__ __forceinline__ const float* cell_ptr(
    const float* p0, const float* p1, const float* p2, int b, int n,
    int& lvl, int& a, int& gi, int& gj, float& stride) {
  const float* src; int G, m;
  if (n < kN0)            { src = p0; G = kG0; lvl = 0; m = n;             stride = 32.f; }
  else if (n < kN0 + kN1) { src = p1; G = kG1; lvl = 1; m = n - kN0;       stride = 16.f; }
  else                    { src = p2; G = kG2; lvl = 2; m = n - kN0 - kN1; stride = 8.f; }
  int gg = G * G;
  a = m / gg;
  int r = m - a * gg;
  gi = r / G;
  gj = r - gi * G;
  return src + (size_t)((((b * 3 + a) * G + gi) * G + gj)) * 26;
}

// ---------------- wave (64-lane) helpers ----------------
__device__ __forceinline__ void waveArgmax(float& v, int& i) {
  #pragma unroll
  for (int off = 1; off < 64; off <<= 1) {
    float ov = __shfl_xor(v, off);
    int oi = __shfl_xor(i, off);
    if (ov > v || (ov == v && oi < i)) { v = ov; i = oi; }
  }
}
__device__ __forceinline__ float waveMax(float v) {
  #pragma unroll
  for (int off = 1; off < 64; off <<= 1) v = fmaxf(v, __shfl_xor(v, off));
  return v;
}
__device__ __forceinline__ float sel4f(const float a[4], int q) {
  float r = a[0];
  r = (q == 1) ? a[1] : r;
  r = (q == 2) ? a[2] : r;
  r = (q == 3) ? a[3] : r;
  return r;
}
__device__ __forceinline__ int sel4i(const int a[4], int q) {
  int r = a[0];
  r = (q == 1) ? a[1] : r;
  r = (q == 2) ? a[2] : r;
  r = (q == 3) ? a[3] : r;
  return r;
}

// ---------------- kernel 1: pipelined tiled score -> keys (NT staging) ----------------
// 1920 blocks x 3 tiles, double-buffered LDS. Staging = coalesced non-temporal u64 loads
// into registers (next tile) overlapped with compute (current tile); regs->LDS after.
// u64 alignment holds for ALL tile bases (104 = 8*13), so no level-0 special case.
__global__ __launch_bounds__(256) void score_kernel(
    const float* __restrict__ p0, const float* __restrict__ p1, const float* __restrict__ p2,
    unsigned* __restrict__ keys)
{
  __shared__ float2 lds2[2][256 * 13];   // 2 x 26624 B

  int t = threadIdx.x;

  // wave-uniform tile parameters for the 3 tiles of this block
  const float2* g2[kTilesPerBlk]; int nc[kTilesPerBlk], n0[kTilesPerBlk], bb[kTilesPerBlk];
  #pragma unroll
  for (int j = 0; j < kTilesPerBlk; ++j) {
    int tileId = (int)blockIdx.x + j * kGridScore;
    int b = tileId / kTilesPerImg;
    int r = tileId - b * kTilesPerImg;
    const float* slab; int NL, lvlOff, tile;
    if (r < kT0)            { slab = p0; NL = kN0; lvlOff = 0;         tile = r; }
    else if (r < kT0 + kT1) { slab = p1; NL = kN1; lvlOff = kN0;       tile = r - kT0; }
    else                    { slab = p2; NL = kN2; lvlOff = kN0 + kN1; tile = r - kT0 - kT1; }
    int cellBase = tile * 256;
    nc[j] = min(256, NL - cellBase);
    g2[j] = (const float2*)(slab + ((size_t)b * NL + cellBase) * 26);
    n0[j] = lvlOff + cellBase;
    bb[j] = b;
  }

  float2 nxt[13];

  // prologue: NT-load tile 0 -> regs -> LDS buf 0
  {
    int tot = nc[0] * 13;
    #pragma unroll
    for (int k = 0; k < 13; ++k) {
      int i = t + k * 256;
      if (i < tot) nxt[k] = nt_load_f2(g2[0] + i);
    }
    #pragma unroll
    for (int k = 0; k < 13; ++k) {
      int i = t + k * 256;
      if (i < tot) lds2[0][i] = nxt[k];
    }
  }

  #pragma unroll
  for (int j = 0; j < kTilesPerBlk; ++j) {
    __syncthreads();   // LDS writes of buf j&1 visible; prev compute done

    // issue NT loads for tile j+1 (in flight during compute below)
    int totN = 0;
    if (j + 1 < kTilesPerBlk) {
      totN = nc[j + 1] * 13;
      #pragma unroll
      for (int k = 0; k < 13; ++k) {
        int i = t + k * 256;
        if (i < totN) nxt[k] = nt_load_f2(g2[j + 1] + i);
      }
    }

    // compute tile j from LDS buf j&1
    int curNc = nc[j], curN0 = n0[j], curB = bb[j];
    const float2* bufp = &lds2[j & 1][0];
    if (t < curNc) {
      const float2* c2 = &bufp[t * 13];   // stride-26-dword: 2-way bank alias (free, m136)
      float2 ol = c2[2];                  // channels 4,5
      float obj = fsigm(ol.x);
      float loc = fsigm(ol.y);
      float tch[20];
      #pragma unroll
      for (int q = 0; q < 10; ++q) { float2 v = c2[3 + q]; tch[2*q] = v.x; tch[2*q+1] = v.y; }
      float lm = tch[0];
      #pragma unroll
      for (int c = 1; c < 20; ++c) lm = fmaxf(lm, tch[c]);
      float se = 0.f;
      #pragma unroll
      for (int c = 0; c < 20; ++c) se += fexpf(tch[c] - lm);
      float cls_conf = frcpf(se);         // max of softmax == exp(0)/sum
      float conf = obj * cls_conf;
      float masked = (obj >= 0.6f && loc >= 0.5f && conf >= 0.05f)
                     ? sqrtf(conf) * sqrtf(loc) : kNEG;  // (obj*cc)^.5 * loc^.5
      keys[(size_t)curB * kNP + curN0 + t] = score_to_key(masked);  // coalesced u32 store
    }

    // regs -> other LDS buffer (after compute; next iter's barrier publishes it)
    if (j + 1 < kTilesPerBlk) {
      float2* dst = &lds2[(j + 1) & 1][0];
      #pragma unroll
      for (int k = 0; k < 13; ++k) {
        int i = t + k * 256;
        if (i < totN) dst[i] = nxt[k];
      }
    }
  }
}

// ---------------- parallel threshold-bin finder ----------------
// Largest bin B with suffix_count(B) >= needed; cumAbove = count strictly above B; total = all.
// All 512 threads participate uniformly.
__device__ __forceinline__ void findThresholdBin(
    const int* hist, int NB, int needed,
    int& outB, int& outCumAbove, int& outTotal,
    int* shWave, int* shOut)
{
  int tid = threadIdx.x, lane = tid & 63, w = tid >> 6;
  if (tid == 0) { shOut[0] = -1; shOut[1] = 0; }
  int ipt = (NB + 511) / 512;
  int base = tid * ipt;
  int csum = 0;
  for (int i = 0; i < ipt; ++i) { int bn = base + i; if (bn < NB) csum += hist[bn]; }
  // inclusive suffix scan within wave (lane l gets sum over lanes >= l)
  int v = csum;
  #pragma unroll
  for (int off = 1; off < 64; off <<= 1) {
    int tv = __shfl_down(v, off);
    if (lane + off < 64) v += tv;
  }
  if (lane == 0) shWave[w] = v;   // wave total
  __syncthreads();
  int above = 0, total = 0;
  #pragma unroll
  for (int q = 0; q < 8; ++q) {
    int wt = shWave[q];
    total += wt;
    if (q > w) above += wt;
  }
  int S = v + above;              // suffix count including own chunk
  if (S >= needed && S - csum < needed) {   // exactly one thread's chunk crosses
    int running = S - csum;
    for (int i = ipt - 1; i >= 0; --i) {
      int bn = base + i; if (bn >= NB) continue;
      int c = hist[bn];
      if (running + c >= needed) { shOut[0] = bn; shOut[1] = running; break; }
      running += c;
    }
  }
  __syncthreads();
  outB = shOut[0]; outCumAbove = shOut[1]; outTotal = total;
  __syncthreads();
}

constexpr int kNV4 = kN / 4;        // 5685 full uint4 per image row (covers 22740)
constexpr int kTail = kN - kNV4*4;  // 3 scalar tail elements

// ---------------- kernel 2: FUSED select (all 512 thr) + soft-NMS (wave 0) ----------------
// Radix top-256 in LDS, then wave 0 runs register-resident NMS. Sweeps are uint4-vectorized
// (key rows padded to kNP -> 16B-aligned); pad element never read.
__global__ __launch_bounds__(512) void select_nms_kernel(
    const unsigned* __restrict__ keys,
    const float* __restrict__ p0, const float* __restrict__ p1, const float* __restrict__ p2,
    float* __restrict__ out)
{
  int b = blockIdx.x, tid = threadIdx.x;
  const unsigned* kk = keys + (size_t)b * kNP;
  const uint4* kk4 = (const uint4*)kk;      // row base b*kNP*4 = b*90976 (16-aligned)
  const unsigned keyNEG = score_to_key(kNEG);

  __shared__ int hist[4096];
  __shared__ int eqBuf[1024];
  __shared__ int shWave[8], shOut[2];
  __shared__ unsigned sT;
  __shared__ int sCgt;
  __shared__ int ciL[kM];
  __shared__ unsigned ckL[kM];

  // ---- pass 1: top 12 bits (skip NEG keys to avoid one-bin atomic hammering) ----
  for (int i = tid; i < 4096; i += 512) hist[i] = 0;
  __syncthreads();
  for (int x = tid; x < kNV4; x += 512) {
    uint4 v = kk4[x];
    if (v.x >= 0x80000000u) atomicAdd(&hist[v.x >> 20], 1);
    if (v.y >= 0x80000000u) atomicAdd(&hist[v.y >> 20], 1);
    if (v.z >= 0x80000000u) atomicAdd(&hist[v.z >> 20], 1);
    if (v.w >= 0x80000000u) atomicAdd(&hist[v.w >> 20], 1);
  }
  if (tid < kTail) {
    unsigned k = kk[kNV4 * 4 + tid];
    if (k >= 0x80000000u) atomicAdd(&hist[k >> 20], 1);
  }
  __syncthreads();
  int B, cumAbove1, total1;
  findThresholdBin(hist, 4096, kM, B, cumAbove1, total1, shWave, shOut);

  if (total1 < kM) {
    if (tid == 0) { sT = keyNEG; sCgt = total1; }   // fewer than 256 valid
    __syncthreads();
  } else {
    int needed2 = kM - cumAbove1;
    // ---- pass 2: key bits 19:8 within bin B ----
    for (int i = tid; i < 4096; i += 512) hist[i] = 0;
    __syncthreads();
    for (int x = tid; x < kNV4; x += 512) {
      uint4 v = kk4[x];
      if ((int)(v.x >> 20) == B) atomicAdd(&hist[(v.x >> 8) & 0xFFF], 1);
      if ((int)(v.y >> 20) == B) atomicAdd(&hist[(v.y >> 8) & 0xFFF], 1);
      if ((int)(v.z >> 20) == B) atomicAdd(&hist[(v.z >> 8) & 0xFFF], 1);
      if ((int)(v.w >> 20) == B) atomicAdd(&hist[(v.w >> 8) & 0xFFF], 1);
    }
    if (tid < kTail) {
      unsigned k = kk[kNV4 * 4 + tid];
      if ((int)(k >> 20) == B) atomicAdd(&hist[(k >> 8) & 0xFFF], 1);
    }
    __syncthreads();
    int B2, cumAbove2, total2;
    findThresholdBin(hist, 4096, needed2, B2, cumAbove2, total2, shWave, shOut);
    int prefix24 = (B << 12) | B2;
    int needed3 = needed2 - cumAbove2;

    // ---- pass 3: low 8 key bits within 24-bit prefix ----
    for (int i = tid; i < 256; i += 512) hist[i] = 0;
    __syncthreads();
    for (int x = tid; x < kNV4; x += 512) {
      uint4 v = kk4[x];
      if ((int)(v.x >> 8) == prefix24) atomicAdd(&hist[v.x & 0xFF], 1);
      if ((int)(v.y >> 8) == prefix24) atomicAdd(&hist[v.y & 0xFF], 1);
      if ((int)(v.z >> 8) == prefix24) atomicAdd(&hist[v.z & 0xFF], 1);
      if ((int)(v.w >> 8) == prefix24) atomicAdd(&hist[v.w & 0xFF], 1);
    }
    if (tid < kTail) {
      unsigned k = kk[kNV4 * 4 + tid];
      if ((int)(k >> 8) == prefix24) atomicAdd(&hist[k & 0xFF], 1);
    }
    __syncthreads();
    int B3, cumAbove3, total3;
    findThresholdBin(hist, 256, needed3, B3, cumAbove3, total3, shWave, shOut);
    if (tid == 0) {
      sT = ((unsigned)prefix24 << 8) | (unsigned)B3;
      sCgt = cumAbove1 + cumAbove2 + cumAbove3;     // exact count of keys > T
    }
    __syncthreads();
  }

  unsigned T = sT;
  int cgt = sCgt;

  // ---- gather into LDS: all keys > T, then fill ties (== T) by smallest index ----
  __shared__ int sCnt, eqCnt;
  if (tid == 0) { sCnt = 0; eqCnt = 0; }
  __syncthreads();
  for (int x = tid; x < kNV4; x += 512) {
    uint4 v = kk4[x];
    int i4 = x * 4;
    unsigned kv[4] = {v.x, v.y, v.z, v.w};
    #pragma unroll
    for (int e = 0; e < 4; ++e) {
      unsigned k = kv[e];
      if (k > T) {
        int p = atomicAdd(&sCnt, 1);
        ciL[p] = i4 + e; ckL[p] = k;
      } else if (k == T && T != keyNEG) {
        int p = atomicAdd(&eqCnt, 1); if (p < 1024) eqBuf[p] = i4 + e;
      }
    }
  }
  if (tid < kTail) {
    int x = kNV4 * 4 + tid;
    unsigned k = kk[x];
    if (k > T) {
      int p = atomicAdd(&sCnt, 1);
      ciL[p] = x; ckL[p] = k;
    } else if (k == T && T != keyNEG) {
      int p = atomicAdd(&eqCnt, 1); if (p < 1024) eqBuf[p] = x;
    }
  }
  __syncthreads();

  int needed = kM - cgt;  // >= 1 by construction
  if (T == keyNEG) {
    // NEG filler candidates: never kept, never picked, never influence others -> dummies ok
    if (tid >= cgt && tid < kM) { ciL[tid] = -1; ckL[tid] = keyNEG; }
  } else {
    int ce = min(eqCnt, 1024);
    if (ce == needed) {               // common case (typically ce == needed == 1)
      if (tid < needed) { ciL[cgt + tid] = eqBuf[tid]; ckL[cgt + tid] = T; }
    } else if (tid == 0) {            // rare tie overflow: take smallest original indices
      for (int q = 0; q < needed; ++q) {
        int mv = INT_MAX, mp = 0;
        for (int x = 0; x < ce; ++x) if (eqBuf[x] < mv) { mv = eqBuf[x]; mp = x; }
        ciL[cgt + q] = mv; ckL[cgt + q] = T; eqBuf[mp] = INT_MAX;
      }
    }
  }
  __syncthreads();

  // ================= NMS phase: wave 0 only, 4 candidates/lane, register state =========
  if (tid >= 64) return;
  int lane = tid;

  float x1[4], y1[4], x2[4], y2[4], val[4], s[4];
  int cls[4];
  bool kept[4];

  #pragma unroll
  for (int q = 0; q < 4; ++q) {
    int slot = q * 64 + lane;
    int n = ciL[slot];
    float sc = key_to_score(ckL[slot]);  // bit-exact score from kernel 1 (kNEG for filler)
    kept[q] = false;
    x1[q] = y1[q] = x2[q] = y2[q] = 0.f;
    cls[q] = 0; val[q] = sc; s[q] = sc;
    if (n >= 0) {
      int lvl, a, gi, gj; float stride;
      const float* p = cell_ptr(p0, p1, p2, b, n, lvl, a, gi, gj, stride);
      const float2* r2 = (const float2*)p;   // rows are 104 B: even-float offsets 8B-aligned
      float2 c01 = r2[0], c23 = r2[1];
      float cx = (fsigm(c01.x) + (float)gj) * stride;
      float cy = (fsigm(c01.y) + (float)gi) * stride;
      float w = fexpf(c23.x) * c_anchors[lvl][a][0];  // (exp*anc/stride)*stride == exp*anc
      float h = fexpf(c23.y) * c_anchors[lvl][a][1];
      x1[q] = fminf(fmaxf(cx - 0.5f * w, 0.f), 608.f);
      y1[q] = fminf(fmaxf(cy - 0.5f * h, 0.f), 608.f);
      x2[q] = fminf(fmaxf(cx + 0.5f * w, 0.f), 608.f);
      y2[q] = fminf(fmaxf(cy + 0.5f * h, 0.f), 608.f);
      float lm = -3.4e38f; int mc = 0;
      #pragma unroll
      for (int j = 3; j < 13; ++j) {
        float2 v = r2[j];
        int c0 = 2 * (j - 3);
        if (v.x > lm) { lm = v.x; mc = c0; }
        if (v.y > lm) { lm = v.y; mc = c0 + 1; }
      }
      cls[q] = mc;
    }
  }

  // top-8 kept ORIGINAL scores, maintained identically (uniformly) on all lanes
  float top8[8];
  #pragma unroll
  for (int i = 0; i < 8; ++i) top8[i] = kNEG;
  int keptCount = 0;

  for (int it = 0; it < kM; ++it) {
    float bv = s[0]; int bq = 0;
    #pragma unroll
    for (int q = 1; q < 4; ++q) if (s[q] > bv) { bv = s[q]; bq = q; }
    int bi = bq * 64 + lane;
    waveArgmax(bv, bi);
    if (bv < 0.1f) break;   // all remaining reference steps are no-ops -> exact

    int wlane = bi & 63, wq = bi >> 6;
    float jx1 = __shfl(sel4f(x1, wq), wlane);
    float jy1 = __shfl(sel4f(y1, wq), wlane);
    float jx2 = __shfl(sel4f(x2, wq), wlane);
    float jy2 = __shfl(sel4f(y2, wq), wlane);
    float jval = __shfl(sel4f(val, wq), wlane);
    int   cj  = __shfl(sel4i(cls, wq), wlane);

    float a1 = (jx2 - jx1 + 1.0f) * (jy2 - jy1 + 1.0f);
    #pragma unroll
    for (int q = 0; q < 4; ++q) {
      if (cls[q] == cj) {
        float ix1 = fmaxf(jx1, x1[q]), iy1 = fmaxf(jy1, y1[q]);
        float ix2 = fminf(jx2, x2[q]), iy2 = fminf(jy2, y2[q]);
        float inter = fmaxf(ix2 - ix1 + 1.0f, 0.0f) * fmaxf(iy2 - iy1 + 1.0f, 0.0f);
        float a2 = (x2[q] - x1[q] + 1.0f) * (y2[q] - y1[q] + 1.0f);
        float iou = inter / (a1 + a2 - inter + 1e-16f);
        s[q] *= fexpf(-(iou * iou) * 2.0f);
      }
      if (bi == q * 64 + lane) { kept[q] = true; s[q] = kNEG; }  // winner slot
    }

    // early-stop bookkeeping (uniform scalar work on every lane)
    float v = jval;
    #pragma unroll
    for (int i = 0; i < 8; ++i) { float m = fmaxf(top8[i], v); v = fminf(top8[i], v); top8[i] = m; }
    ++keptCount;
    if (keptCount >= kTopK) {
      float am = kNEG;
      #pragma unroll
      for (int q = 0; q < 4; ++q) if (s[q] >= 0.1f) am = fmaxf(am, val[q]);
      am = waveMax(am);
      // no alive candidate's ORIGINAL score can beat the 8th-best kept original:
      // s is monotone non-increasing, originals fixed, kept flags never revert -> exact stop
      if (am < top8[7]) break;
    }
  }

  // keep_top_k by ORIGINAL score among kept
  float f[4];
  #pragma unroll
  for (int q = 0; q < 4; ++q) f[q] = kept[q] ? val[q] : kNEG;
  for (int k = 0; k < kTopK; ++k) {
    float bv = f[0]; int bq = 0;
    #pragma unroll
    for (int q = 1; q < 4; ++q) if (f[q] > bv) { bv = f[q]; bq = q; }
    int bi = bq * 64 + lane;
    waveArgmax(bv, bi);
    int wlane = bi & 63, wq = bi >> 6;
    if (lane == wlane) {
      float* o = out + (size_t)(b * kTopK + k) * 6;
      if (bv > kNEG * 0.5f) {
        o[0] = sel4f(x1, wq); o[1] = sel4f(y1, wq);
        o[2] = sel4f(x2, wq); o[3] = sel4f(y2, wq);
        o[4] = sel4f(val, wq); o[5] = (float)sel4i(cls, wq);
      } else {
        o[0] = 0.f; o[1] = 0.f; o[2] = 0.f; o[3] = 0.f; o[4] = 0.f; o[5] = 0.f;
      }
    }
    #pragma unroll
    for (int q = 0; q < 4; ++q) if (bi == q * 64 + lane) f[q] = kNEG;
  }
}

// ---------------- host launch ----------------
extern "C" void kernel_launch(void* const* d_in, const int* in_sizes, int n_in,
                              void* d_out, int out_size, void* d_ws, size_t ws_size,
                              hipStream_t stream) {
  const float* p0 = (const float*)d_in[0];
  const float* p1 = (const float*)d_in[1];
  const float* p2 = (const float*)d_in[2];
  float* out = (float*)d_out;

  // workspace layout: keys u32[B*kNP] (5.82 MB; rows padded to 22744 for 16B alignment)
  unsigned* keys = (unsigned*)d_ws;

  score_kernel<<<kGridScore, 256, 0, stream>>>(p0, p1, p2, keys);
  select_nms_kernel<<<kB, 512, 0, stream>>>(keys, p0, p1, p2, out);
}